// Round 10
// baseline (249.474 us; speedup 1.0000x reference)
//
#include <hip/hip_runtime.h>

#define SEQ     2048
#define HDIM    1024
#define TOKENS  4096   // B*SEQ
#define NHEADS  16
#define HS      64
#define LP      72     // padded LDS row stride (elements): 144B, 16B-aligned

typedef __bf16 v8bf __attribute__((ext_vector_type(8)));
typedef float  v4f  __attribute__((ext_vector_type(4)));

#define MFMA16(a, b, c) __builtin_amdgcn_mfma_f32_16x16x32_bf16((a), (b), (c), 0, 0, 0)

// scores arrive in log2 units: 1/sqrt(64) * log2(e) folded into Q pre-scale
#define QSCALE (0.125f * 1.44269504088896f)

__device__ __forceinline__ unsigned short f2bf(float f) {
  unsigned int u = __float_as_uint(f);
  u += 0x7FFFu + ((u >> 16) & 1u);   // RNE
  return (unsigned short)(u >> 16);
}

__device__ __forceinline__ void async16(const void* g, void* l) {
  __builtin_amdgcn_global_load_lds(
      (const __attribute__((address_space(1))) void*)g,
      (__attribute__((address_space(3))) void*)l, 16, 0, 0);
}

// ---------------- fused prep: x casts + both weight transposes ----------------
__global__ __launch_bounds__(256) void prep_all_kernel(
    const float* __restrict__ x, const float* __restrict__ pos,
    const float* __restrict__ Wqkv, const float* __restrict__ Wout,
    unsigned short* __restrict__ X, unsigned short* __restrict__ XP,
    unsigned short* __restrict__ WQT, unsigned short* __restrict__ WOT) {
  __shared__ float tile[32][33];
  const int id = blockIdx.x;
  if (id < 4096) {
    const int i = (id * 256 + threadIdx.x) * 4;
    float4 xv = *(const float4*)(x + i);
    float4 pv = *(const float4*)(pos + (i & (SEQ * HDIM - 1)));
    ushort4 a, b;
    a.x = f2bf(xv.x); a.y = f2bf(xv.y); a.z = f2bf(xv.z); a.w = f2bf(xv.w);
    b.x = f2bf(xv.x + pv.x); b.y = f2bf(xv.y + pv.y);
    b.z = f2bf(xv.z + pv.z); b.w = f2bf(xv.w + pv.w);
    *(ushort4*)(X + i) = a;
    *(ushort4*)(XP + i) = b;
    return;
  }
  const float* in; unsigned short* out; int R, C, bx, by;
  if (id < 7168) {
    const int t2 = id - 4096;
    in = Wqkv; out = WQT; R = HDIM; C = 3 * HDIM;
    bx = (t2 % 96) * 32; by = (t2 / 96) * 32;
  } else {
    const int t3 = id - 7168;
    in = Wout; out = WOT; R = HDIM; C = HDIM;
    bx = (t3 & 31) * 32; by = (t3 >> 5) * 32;
  }
  const int tx = threadIdx.x & 31, ty = threadIdx.x >> 5;  // (32,8)
#pragma unroll
  for (int j = 0; j < 32; j += 8)
    tile[ty + j][tx] = in[(size_t)(by + ty + j) * C + bx + tx];
  __syncthreads();
#pragma unroll
  for (int j = 0; j < 32; j += 8)
    out[(size_t)(bx + ty + j) * R + by + tx] = f2bf(tile[tx][ty + j]);
}

// ---------------- GEMM1: C(4096x3072) = Aeff(4096x1024) @ Wt(3072x1024)^T ----------------
// BK=64 (two 32-wide LDS sub-buffers per iter): halves barrier count vs BK=32.
// V blocks compute C^T via operand swap so the V^T store is 32B s-runs.
__global__ __launch_bounds__(256) void gemm_qkv_kernel(
    const unsigned short* __restrict__ XP, const unsigned short* __restrict__ X,
    const unsigned short* __restrict__ Wt,
    unsigned short* __restrict__ Qb, unsigned short* __restrict__ Kb,
    unsigned short* __restrict__ VTb) {
  __shared__ unsigned short As[2][128 * 32];
  __shared__ unsigned short Bs[2][128 * 32];
  const int m0 = blockIdx.x * 128;
  const int n0 = blockIdx.y * 128;
  const bool isV = (n0 >= 2 * HDIM);
  const unsigned short* A = isV ? X : XP;
  const int t = threadIdx.x;
  const int lane = t & 63, w = t >> 6;
  const int wm = (w >> 1) * 64, wn = (w & 1) * 64;
  const int quad = lane >> 4, l15 = lane & 15;

  v4f acc[4][4] = {};

  const int rowA = t >> 2;          // 0..63
  const int colA = (t & 3) * 8;
  const unsigned short* gA = A + (size_t)(m0 + rowA) * HDIM + colA;
  const unsigned short* gB = Wt + (size_t)(n0 + rowA) * HDIM + colA;

  for (int k0 = 0; k0 < HDIM; k0 += 64) {
    __syncthreads();
#pragma unroll
    for (int kh = 0; kh < 2; kh++) {
      async16(gA + k0 + kh * 32, &As[kh][t * 8]);
      async16(gA + 64 * HDIM + k0 + kh * 32, &As[kh][2048 + t * 8]);
      async16(gB + k0 + kh * 32, &Bs[kh][t * 8]);
      async16(gB + 64 * HDIM + k0 + kh * 32, &Bs[kh][2048 + t * 8]);
    }
    __syncthreads();
#pragma unroll
    for (int kh = 0; kh < 2; kh++) {
      v8bf a[4], b[4];
#pragma unroll
      for (int i = 0; i < 4; i++)
        a[i] = *(const v8bf*)&As[kh][(wm + i * 16 + l15) * 32 + quad * 8];
#pragma unroll
      for (int i = 0; i < 4; i++)
        b[i] = *(const v8bf*)&Bs[kh][(wn + i * 16 + l15) * 32 + quad * 8];
      if (isV) {
#pragma unroll
        for (int i = 0; i < 4; i++)
#pragma unroll
          for (int j = 0; j < 4; j++)
            acc[i][j] = MFMA16(b[j], a[i], acc[i][j]);   // C^T
      } else {
#pragma unroll
        for (int i = 0; i < 4; i++)
#pragma unroll
          for (int j = 0; j < 4; j++)
            acc[i][j] = MFMA16(a[i], b[j], acc[i][j]);
      }
    }
  }

  const int b_ = m0 >> 11;
  const int s0 = m0 & (SEQ - 1);

  if (isV) {
    // acc[i][j] = C^T: D[row=quad*4+r -> Wt col (d)][col=l15 -> token (s)]
#pragma unroll
    for (int i = 0; i < 4; i++) {
#pragma unroll
      for (int j = 0; j < 4; j++) {
        const int s_ = s0 + wm + i * 16 + l15;
#pragma unroll
        for (int r = 0; r < 4; r++) {
          const int c2 = (n0 - 2 * HDIM) + wn + j * 16 + quad * 4 + r;
          const int h = c2 >> 6, d = c2 & 63;
          VTb[((size_t)(((b_ << 4) | h) * HS + d)) * SEQ + s_] = f2bf(acc[i][j][r]);
        }
      }
    }
  } else {
    // Q/K[(b,h,s), d]: scatter, 16 consecutive lanes form 32B d-runs
    const float scale = (n0 < HDIM) ? QSCALE : 1.0f;
    unsigned short* dst = (n0 < HDIM) ? Qb : Kb;
#pragma unroll
    for (int i = 0; i < 4; i++) {
#pragma unroll
      for (int j = 0; j < 4; j++) {
#pragma unroll
        for (int r = 0; r < 4; r++) {
          const int s_ = s0 + wm + i * 16 + quad * 4 + r;
          const int c2 = (n0 & (HDIM - 1)) + wn + j * 16 + l15;
          const int h = c2 >> 6, d = c2 & 63;
          dst[((size_t)(((b_ << 4) | h) * SEQ + s_)) * HS + d] =
              f2bf(acc[i][j][r] * scale);
        }
      }
    }
  }
}

// ---------------- flash attention, complementary-pair balanced + Qs/Ps union --------
// Block (bh, p): q-tiles qlo=p and qhi=31-p (64 rows each), one K/V stream over
// chunks 0..qhi; exactly 33 chunk-tiles per block. Qs (dead after fragment
// load) is overlaid by per-wave Ps => LDS 36,864 B => 4 blocks/CU, 16 waves/CU.
__global__ __launch_bounds__(256, 4) void attn_pair_kernel(
    const unsigned short* __restrict__ Qp, const unsigned short* __restrict__ Kp,
    const unsigned short* __restrict__ Vp, unsigned short* __restrict__ ATTN) {
  __shared__ unsigned short SM[18432];       // 36,864 B
  unsigned short* Ks = SM;                   // 64*LP
  unsigned short* Vs = SM + 4608;            // 64*LP (V^T chunk: [d][key])
  unsigned short* QPs = SM + 9216;           // 128*LP union: Qs (init) / Ps (loop)

  const int bh = blockIdx.x;
  const int p  = blockIdx.y;        // 0..15
  const int b_ = bh >> 4, h = bh & 15;
  const int qlo = p, qhi = 31 - p;
  const int q0lo = qlo * 64, q0hi = qhi * 64;
  const int t = threadIdx.x;
  const int lane = t & 63, w = t >> 6;
  const int quad = lane >> 4, l15 = lane & 15;

  const unsigned short* Qg = Qp + (size_t)bh * SEQ * HS;
  const unsigned short* Kg = Kp + (size_t)bh * SEQ * HS;
  const unsigned short* Vg = Vp + (size_t)bh * HS * SEQ;

  const int sr = t >> 3, scol = (t & 7) * 8;
  *(uint4*)&QPs[sr * LP + scol] = *(const uint4*)(Qg + (size_t)(q0lo + sr) * HS + scol);
  *(uint4*)&QPs[(sr + 32) * LP + scol] =
      *(const uint4*)(Qg + (size_t)(q0lo + sr + 32) * HS + scol);
  *(uint4*)&QPs[(sr + 64) * LP + scol] =
      *(const uint4*)(Qg + (size_t)(q0hi + sr) * HS + scol);
  *(uint4*)&QPs[(sr + 96) * LP + scol] =
      *(const uint4*)(Qg + (size_t)(q0hi + sr + 32) * HS + scol);
  __syncthreads();

  // Q rows as B-operand fragments: [tile][khalf]. After these ds_reads drain
  // (at the first in-loop __syncthreads), QPs is reused as per-wave Ps.
  v8bf bq[2][2];
#pragma unroll
  for (int tl = 0; tl < 2; tl++)
#pragma unroll
    for (int kh = 0; kh < 2; kh++)
      bq[tl][kh] = *(const v8bf*)&QPs[(tl * 64 + w * 16 + l15) * LP + kh * 32 + quad * 8];

  unsigned short* Ps_w = QPs + w * 32 * LP;  // 32 rows/wave: 0-15 lo, 16-31 hi

  v8bf ones;
#pragma unroll
  for (int j = 0; j < 8; j++) ones[j] = (__bf16)1.0f;

  v4f o[2][4] = {};
  v4f lacc[2] = {};

  // register prefetch of chunk 0
  uint4 kr0, kr1, vr0, vr1;
  kr0 = *(const uint4*)(Kg + (size_t)sr * HS + scol);
  kr1 = *(const uint4*)(Kg + (size_t)(sr + 32) * HS + scol);
  vr0 = *(const uint4*)(Vg + (size_t)sr * SEQ + scol);
  vr1 = *(const uint4*)(Vg + (size_t)(sr + 32) * SEQ + scol);

  const int qrow_hi = q0hi + w * 16 + l15;  // lane's q-row in S^T
  const int qrow_lo = q0lo + w * 16 + l15;

  for (int cI = 0; cI <= qhi; cI++) {
    const int kc = cI * 64;
    __syncthreads();  // previous chunk's K/V (and init bq) LDS reads done
    *(uint4*)&Ks[sr * LP + scol] = kr0;
    *(uint4*)&Ks[(sr + 32) * LP + scol] = kr1;
    *(uint4*)&Vs[sr * LP + scol] = vr0;
    *(uint4*)&Vs[(sr + 32) * LP + scol] = vr1;
    if (cI < qhi) {  // prefetch next chunk while computing this one
      const int kn = kc + 64;
      kr0 = *(const uint4*)(Kg + (size_t)(kn + sr) * HS + scol);
      kr1 = *(const uint4*)(Kg + (size_t)(kn + sr + 32) * HS + scol);
      vr0 = *(const uint4*)(Vg + (size_t)sr * SEQ + kn + scol);
      vr1 = *(const uint4*)(Vg + (size_t)(sr + 32) * SEQ + kn + scol);
    }
    __syncthreads();

    // K fragments (A-operand), shared across both tiles
    v8bf kf0[4], kf1[4];
#pragma unroll
    for (int ni = 0; ni < 4; ni++) {
      kf0[ni] = *(const v8bf*)&Ks[(ni * 16 + l15) * LP + quad * 8];
      kf1[ni] = *(const v8bf*)&Ks[(ni * 16 + l15) * LP + 32 + quad * 8];
    }

    const bool doLo = (cI <= qlo);

    // ---- hi tile: S^T = K Q^T, D[key=quad*4+r][qrow=l15] ----
    {
      v4f sc[4] = {};
#pragma unroll
      for (int ni = 0; ni < 4; ni++) {
        sc[ni] = MFMA16(kf0[ni], bq[1][0], sc[ni]);
        sc[ni] = MFMA16(kf1[ni], bq[1][1], sc[ni]);
      }
      if (cI == qhi) {
#pragma unroll
        for (int ni = 0; ni < 4; ni++) {
          const int key = kc + ni * 16 + quad * 4;
#pragma unroll
          for (int r = 0; r < 4; r++)
            if (key + r > qrow_hi) sc[ni][r] = -1e30f;
        }
      }
#pragma unroll
      for (int ni = 0; ni < 4; ni++) {
        const float p0 = exp2f(sc[ni][0]), p1 = exp2f(sc[ni][1]);
        const float p2 = exp2f(sc[ni][2]), p3 = exp2f(sc[ni][3]);
        uint2 pk;
        pk.x = __builtin_amdgcn_perm(__float_as_uint(p1), __float_as_uint(p0), 0x07060302u);
        pk.y = __builtin_amdgcn_perm(__float_as_uint(p3), __float_as_uint(p2), 0x07060302u);
        *(uint2*)&Ps_w[(16 + l15) * LP + ni * 16 + quad * 4] = pk;
      }
    }
    // ---- lo tile (wave-uniform skip once cI > qlo) ----
    if (doLo) {
      v4f sc[4] = {};
#pragma unroll
      for (int ni = 0; ni < 4; ni++) {
        sc[ni] = MFMA16(kf0[ni], bq[0][0], sc[ni]);
        sc[ni] = MFMA16(kf1[ni], bq[0][1], sc[ni]);
      }
      if (cI == qlo) {
#pragma unroll
        for (int ni = 0; ni < 4; ni++) {
          const int key = kc + ni * 16 + quad * 4;
#pragma unroll
          for (int r = 0; r < 4; r++)
            if (key + r > qrow_lo) sc[ni][r] = -1e30f;
        }
      }
#pragma unroll
      for (int ni = 0; ni < 4; ni++) {
        const float p0 = exp2f(sc[ni][0]), p1 = exp2f(sc[ni][1]);
        const float p2 = exp2f(sc[ni][2]), p3 = exp2f(sc[ni][3]);
        uint2 pk;
        pk.x = __builtin_amdgcn_perm(__float_as_uint(p1), __float_as_uint(p0), 0x07060302u);
        pk.y = __builtin_amdgcn_perm(__float_as_uint(p3), __float_as_uint(p2), 0x07060302u);
        *(uint2*)&Ps_w[l15 * LP + ni * 16 + quad * 4] = pk;
      }
    }

    // ---- O += P @ V, l += P @ 1; V fragments shared across tiles ----
#pragma unroll
    for (int ki = 0; ki < 2; ki++) {
      v8bf pahi = *(const v8bf*)&Ps_w[(16 + l15) * LP + ki * 32 + quad * 8];
      lacc[1] = MFMA16(pahi, ones, lacc[1]);
      v8bf palo;
      if (doLo) {
        palo = *(const v8bf*)&Ps_w[l15 * LP + ki * 32 + quad * 8];
        lacc[0] = MFMA16(palo, ones, lacc[0]);
      }
#pragma unroll
      for (int ni = 0; ni < 4; ni++) {
        v8bf vb = *(const v8bf*)&Vs[(ni * 16 + l15) * LP + ki * 32 + quad * 8];
        o[1][ni] = MFMA16(pahi, vb, o[1][ni]);
        if (doLo) o[0][ni] = MFMA16(palo, vb, o[0][ni]);
      }
    }
  }

  // epilogue: normalize and store both tiles (C-layout rows = quad*4+r)
#pragma unroll
  for (int tl = 0; tl < 2; tl++) {
    const int q0 = tl ? q0hi : q0lo;
    const int row_base = q0 + w * 16 + quad * 4;
    float invl[4];
#pragma unroll
    for (int r = 0; r < 4; r++) invl[r] = 1.0f / lacc[tl][r];
#pragma unroll
    for (int ni = 0; ni < 4; ni++)
#pragma unroll
      for (int r = 0; r < 4; r++) {
        const int tr = b_ * SEQ + row_base + r;
        ATTN[(size_t)tr * HDIM + h * HS + ni * 16 + l15] = f2bf(o[tl][ni][r] * invl[r]);
      }
  }
}

// ---------------- GEMM2: out(4096x1024) = ATTN @ WOT^T, fp32 out ----------------
// 128x64 tiles -> 512 blocks (2/CU) for latency hiding.
__global__ __launch_bounds__(256) void gemm_out_kernel(
    const unsigned short* __restrict__ Ab, const unsigned short* __restrict__ Wt,
    float* __restrict__ out) {
  __shared__ unsigned short As[128 * 32];
  __shared__ unsigned short Bs[64 * 32];
  const int m0 = blockIdx.x * 128;
  const int n0 = blockIdx.y * 64;
  const int t = threadIdx.x;
  const int lane = t & 63, w = t >> 6;
  const int wm = w * 32;
  const int quad = lane >> 4, l15 = lane & 15;

  v4f acc[2][4] = {};

  const int rowA = t >> 2;
  const int colA = (t & 3) * 8;
  const unsigned short* gA = Ab + (size_t)(m0 + rowA) * HDIM + colA;
  const unsigned short* gB = Wt + (size_t)(n0 + rowA) * HDIM + colA;
  unsigned short* lA = &As[t * 8];
  unsigned short* lB = &Bs[t * 8];   // only first 64 rows' worth used

  for (int k0 = 0; k0 < HDIM; k0 += 32) {
    __syncthreads();
    async16(gA + k0, lA);
    async16(gA + 64 * HDIM + k0, lA + 64 * 32);
    if (rowA < 64) async16(gB + k0, lB);
    __syncthreads();
    v8bf a[2], b[4];
#pragma unroll
    for (int i = 0; i < 2; i++)
      a[i] = *(const v8bf*)&As[(wm + i * 16 + l15) * 32 + quad * 8];
#pragma unroll
    for (int j = 0; j < 4; j++)
      b[j] = *(const v8bf*)&Bs[(j * 16 + l15) * 32 + quad * 8];
#pragma unroll
    for (int i = 0; i < 2; i++)
#pragma unroll
      for (int j = 0; j < 4; j++)
        acc[i][j] = MFMA16(a[i], b[j], acc[i][j]);
  }

#pragma unroll
  for (int i = 0; i < 2; i++) {
#pragma unroll
    for (int j = 0; j < 4; j++) {
#pragma unroll
      for (int r = 0; r < 4; r++) {
        const int tr = m0 + wm + i * 16 + quad * 4 + r;
        const int c = n0 + j * 16 + l15;
        out[(size_t)tr * HDIM + c] = acc[i][j][r];
      }
    }
  }
}

extern "C" void kernel_launch(void* const* d_in, const int* in_sizes, int n_in,
                              void* d_out, int out_size, void* d_ws, size_t ws_size,
                              hipStream_t stream) {
  (void)in_sizes; (void)n_in; (void)out_size; (void)ws_size;
  const float* x    = (const float*)d_in[0];
  const float* pos  = (const float*)d_in[1];
  const float* Wqkv = (const float*)d_in[2];
  const float* Wout = (const float*)d_in[3];
  float* out = (float*)d_out;

  char* ws = (char*)d_ws;
  unsigned short* XP   = (unsigned short*)(ws);
  unsigned short* X    = (unsigned short*)(ws + ((size_t)8  << 20));
  unsigned short* WQT  = (unsigned short*)(ws + ((size_t)16 << 20));
  unsigned short* WOT  = (unsigned short*)(ws + ((size_t)22 << 20));
  unsigned short* Qb   = (unsigned short*)(ws + ((size_t)24 << 20));
  unsigned short* Kb   = (unsigned short*)(ws + ((size_t)32 << 20));
  unsigned short* VTb  = (unsigned short*)(ws + ((size_t)40 << 20));
  unsigned short* ATTN = (unsigned short*)(ws + ((size_t)48 << 20));

  prep_all_kernel<<<8192, 256, 0, stream>>>(x, pos, Wqkv, Wout, X, XP, WQT, WOT);

  dim3 g1(TOKENS / 128, 3 * HDIM / 128);
  gemm_qkv_kernel<<<g1, 256, 0, stream>>>(XP, X, WQT, Qb, Kb, VTb);

  dim3 g2(2 * NHEADS, 16);
  attn_pair_kernel<<<g2, 256, 0, stream>>>(Qb, Kb, VTb, ATTN);

  dim3 g3(TOKENS / 128, HDIM / 64);
  gemm_out_kernel<<<g3, 256, 0, stream>>>(ATTN, WOT, out);
}

// Round 11
// 188.194 us; speedup vs baseline: 1.3256x; 1.3256x over previous
//
#include <hip/hip_runtime.h>

#define SEQ     2048
#define HDIM    1024
#define TOKENS  4096   // B*SEQ
#define NHEADS  16
#define HS      64
#define LP      72     // padded LDS row stride (elements): 144B, 16B-aligned

typedef __bf16 v8bf __attribute__((ext_vector_type(8)));
typedef float  v4f  __attribute__((ext_vector_type(4)));

#define MFMA16(a, b, c) __builtin_amdgcn_mfma_f32_16x16x32_bf16((a), (b), (c), 0, 0, 0)

// scores arrive in log2 units: 1/sqrt(64) * log2(e) folded into Q pre-scale
#define QSCALE (0.125f * 1.44269504088896f)

__device__ __forceinline__ unsigned short f2bf(float f) {
  unsigned int u = __float_as_uint(f);
  u += 0x7FFFu + ((u >> 16) & 1u);   // RNE
  return (unsigned short)(u >> 16);
}

__device__ __forceinline__ void async16(const void* g, void* l) {
  __builtin_amdgcn_global_load_lds(
      (const __attribute__((address_space(1))) void*)g,
      (__attribute__((address_space(3))) void*)l, 16, 0, 0);
}

// ---------------- fused prep: x casts + both weight transposes ----------------
__global__ __launch_bounds__(256) void prep_all_kernel(
    const float* __restrict__ x, const float* __restrict__ pos,
    const float* __restrict__ Wqkv, const float* __restrict__ Wout,
    unsigned short* __restrict__ X, unsigned short* __restrict__ XP,
    unsigned short* __restrict__ WQT, unsigned short* __restrict__ WOT) {
  __shared__ float tile[32][33];
  const int id = blockIdx.x;
  if (id < 4096) {
    const int i = (id * 256 + threadIdx.x) * 4;
    float4 xv = *(const float4*)(x + i);
    float4 pv = *(const float4*)(pos + (i & (SEQ * HDIM - 1)));
    ushort4 a, b;
    a.x = f2bf(xv.x); a.y = f2bf(xv.y); a.z = f2bf(xv.z); a.w = f2bf(xv.w);
    b.x = f2bf(xv.x + pv.x); b.y = f2bf(xv.y + pv.y);
    b.z = f2bf(xv.z + pv.z); b.w = f2bf(xv.w + pv.w);
    *(ushort4*)(X + i) = a;
    *(ushort4*)(XP + i) = b;
    return;
  }
  const float* in; unsigned short* out; int R, C, bx, by;
  if (id < 7168) {
    const int t2 = id - 4096;
    in = Wqkv; out = WQT; R = HDIM; C = 3 * HDIM;
    bx = (t2 % 96) * 32; by = (t2 / 96) * 32;
  } else {
    const int t3 = id - 7168;
    in = Wout; out = WOT; R = HDIM; C = HDIM;
    bx = (t3 & 31) * 32; by = (t3 >> 5) * 32;
  }
  const int tx = threadIdx.x & 31, ty = threadIdx.x >> 5;  // (32,8)
#pragma unroll
  for (int j = 0; j < 32; j += 8)
    tile[ty + j][tx] = in[(size_t)(by + ty + j) * C + bx + tx];
  __syncthreads();
#pragma unroll
  for (int j = 0; j < 32; j += 8)
    out[(size_t)(bx + ty + j) * R + by + tx] = f2bf(tile[tx][ty + j]);
}

// ---------------- GEMM1: C(4096x3072) = Aeff(4096x1024) @ Wt(3072x1024)^T ----------------
// BK=64 (two 32-wide LDS sub-buffers per iter): halves barrier count vs BK=32.
// V blocks compute C^T via operand swap so the V^T store is 32B s-runs.
__global__ __launch_bounds__(256) void gemm_qkv_kernel(
    const unsigned short* __restrict__ XP, const unsigned short* __restrict__ X,
    const unsigned short* __restrict__ Wt,
    unsigned short* __restrict__ Qb, unsigned short* __restrict__ Kb,
    unsigned short* __restrict__ VTb) {
  __shared__ unsigned short As[2][128 * 32];
  __shared__ unsigned short Bs[2][128 * 32];
  const int m0 = blockIdx.x * 128;
  const int n0 = blockIdx.y * 128;
  const bool isV = (n0 >= 2 * HDIM);
  const unsigned short* A = isV ? X : XP;
  const int t = threadIdx.x;
  const int lane = t & 63, w = t >> 6;
  const int wm = (w >> 1) * 64, wn = (w & 1) * 64;
  const int quad = lane >> 4, l15 = lane & 15;

  v4f acc[4][4] = {};

  const int rowA = t >> 2;          // 0..63
  const int colA = (t & 3) * 8;
  const unsigned short* gA = A + (size_t)(m0 + rowA) * HDIM + colA;
  const unsigned short* gB = Wt + (size_t)(n0 + rowA) * HDIM + colA;

  for (int k0 = 0; k0 < HDIM; k0 += 64) {
    __syncthreads();
#pragma unroll
    for (int kh = 0; kh < 2; kh++) {
      async16(gA + k0 + kh * 32, &As[kh][t * 8]);
      async16(gA + 64 * HDIM + k0 + kh * 32, &As[kh][2048 + t * 8]);
      async16(gB + k0 + kh * 32, &Bs[kh][t * 8]);
      async16(gB + 64 * HDIM + k0 + kh * 32, &Bs[kh][2048 + t * 8]);
    }
    __syncthreads();
#pragma unroll
    for (int kh = 0; kh < 2; kh++) {
      v8bf a[4], b[4];
#pragma unroll
      for (int i = 0; i < 4; i++)
        a[i] = *(const v8bf*)&As[kh][(wm + i * 16 + l15) * 32 + quad * 8];
#pragma unroll
      for (int i = 0; i < 4; i++)
        b[i] = *(const v8bf*)&Bs[kh][(wn + i * 16 + l15) * 32 + quad * 8];
      if (isV) {
#pragma unroll
        for (int i = 0; i < 4; i++)
#pragma unroll
          for (int j = 0; j < 4; j++)
            acc[i][j] = MFMA16(b[j], a[i], acc[i][j]);   // C^T
      } else {
#pragma unroll
        for (int i = 0; i < 4; i++)
#pragma unroll
          for (int j = 0; j < 4; j++)
            acc[i][j] = MFMA16(a[i], b[j], acc[i][j]);
      }
    }
  }

  const int b_ = m0 >> 11;
  const int s0 = m0 & (SEQ - 1);

  if (isV) {
    // acc[i][j] = C^T: D[row=quad*4+r -> Wt col (d)][col=l15 -> token (s)]
#pragma unroll
    for (int i = 0; i < 4; i++) {
#pragma unroll
      for (int j = 0; j < 4; j++) {
        const int s_ = s0 + wm + i * 16 + l15;
#pragma unroll
        for (int r = 0; r < 4; r++) {
          const int c2 = (n0 - 2 * HDIM) + wn + j * 16 + quad * 4 + r;
          const int h = c2 >> 6, d = c2 & 63;
          VTb[((size_t)(((b_ << 4) | h) * HS + d)) * SEQ + s_] = f2bf(acc[i][j][r]);
        }
      }
    }
  } else {
    // Q/K[(b,h,s), d]: scatter, 16 consecutive lanes form 32B d-runs
    const float scale = (n0 < HDIM) ? QSCALE : 1.0f;
    unsigned short* dst = (n0 < HDIM) ? Qb : Kb;
#pragma unroll
    for (int i = 0; i < 4; i++) {
#pragma unroll
      for (int j = 0; j < 4; j++) {
#pragma unroll
        for (int r = 0; r < 4; r++) {
          const int s_ = s0 + wm + i * 16 + quad * 4 + r;
          const int c2 = (n0 & (HDIM - 1)) + wn + j * 16 + l15;
          const int h = c2 >> 6, d = c2 & 63;
          dst[((size_t)(((b_ << 4) | h) * SEQ + s_)) * HS + d] =
              f2bf(acc[i][j][r] * scale);
        }
      }
    }
  }
}

// ---------------- flash attention, complementary-pair balanced + Qs/Ps union --------
// Block (bh, p): q-tiles qlo=p and qhi=31-p (64 rows each), one K/V stream over
// chunks 0..qhi; exactly 33 chunk-tiles per block. Qs (dead after fragment
// load) is overlaid by per-wave Ps => LDS 36,864 B => 4 blocks/CU at 88 VGPR.
// NOTE: launch_bounds min-waves MUST stay 2 — forcing 4 caps VGPR at 64 and
// spills ~60MB to scratch (R10: dur 46->109us, WRITE 8->68MB).
__global__ __launch_bounds__(256, 2) void attn_pair_kernel(
    const unsigned short* __restrict__ Qp, const unsigned short* __restrict__ Kp,
    const unsigned short* __restrict__ Vp, unsigned short* __restrict__ ATTN) {
  __shared__ unsigned short SM[18432];       // 36,864 B
  unsigned short* Ks = SM;                   // 64*LP
  unsigned short* Vs = SM + 4608;            // 64*LP (V^T chunk: [d][key])
  unsigned short* QPs = SM + 9216;           // 128*LP union: Qs (init) / Ps (loop)

  const int bh = blockIdx.x;
  const int p  = blockIdx.y;        // 0..15
  const int b_ = bh >> 4, h = bh & 15;
  const int qlo = p, qhi = 31 - p;
  const int q0lo = qlo * 64, q0hi = qhi * 64;
  const int t = threadIdx.x;
  const int lane = t & 63, w = t >> 6;
  const int quad = lane >> 4, l15 = lane & 15;

  const unsigned short* Qg = Qp + (size_t)bh * SEQ * HS;
  const unsigned short* Kg = Kp + (size_t)bh * SEQ * HS;
  const unsigned short* Vg = Vp + (size_t)bh * HS * SEQ;

  const int sr = t >> 3, scol = (t & 7) * 8;
  *(uint4*)&QPs[sr * LP + scol] = *(const uint4*)(Qg + (size_t)(q0lo + sr) * HS + scol);
  *(uint4*)&QPs[(sr + 32) * LP + scol] =
      *(const uint4*)(Qg + (size_t)(q0lo + sr + 32) * HS + scol);
  *(uint4*)&QPs[(sr + 64) * LP + scol] =
      *(const uint4*)(Qg + (size_t)(q0hi + sr) * HS + scol);
  *(uint4*)&QPs[(sr + 96) * LP + scol] =
      *(const uint4*)(Qg + (size_t)(q0hi + sr + 32) * HS + scol);
  __syncthreads();

  // Q rows as B-operand fragments: [tile][khalf]. After these ds_reads drain
  // (at the first in-loop __syncthreads), QPs is reused as per-wave Ps.
  v8bf bq[2][2];
#pragma unroll
  for (int tl = 0; tl < 2; tl++)
#pragma unroll
    for (int kh = 0; kh < 2; kh++)
      bq[tl][kh] = *(const v8bf*)&QPs[(tl * 64 + w * 16 + l15) * LP + kh * 32 + quad * 8];

  unsigned short* Ps_w = QPs + w * 32 * LP;  // 32 rows/wave: 0-15 lo, 16-31 hi

  v8bf ones;
#pragma unroll
  for (int j = 0; j < 8; j++) ones[j] = (__bf16)1.0f;

  v4f o[2][4] = {};
  v4f lacc[2] = {};

  // register prefetch of chunk 0
  uint4 kr0, kr1, vr0, vr1;
  kr0 = *(const uint4*)(Kg + (size_t)sr * HS + scol);
  kr1 = *(const uint4*)(Kg + (size_t)(sr + 32) * HS + scol);
  vr0 = *(const uint4*)(Vg + (size_t)sr * SEQ + scol);
  vr1 = *(const uint4*)(Vg + (size_t)(sr + 32) * SEQ + scol);

  const int qrow_hi = q0hi + w * 16 + l15;  // lane's q-row in S^T
  const int qrow_lo = q0lo + w * 16 + l15;

  for (int cI = 0; cI <= qhi; cI++) {
    const int kc = cI * 64;
    __syncthreads();  // previous chunk's K/V (and init bq) LDS reads done
    *(uint4*)&Ks[sr * LP + scol] = kr0;
    *(uint4*)&Ks[(sr + 32) * LP + scol] = kr1;
    *(uint4*)&Vs[sr * LP + scol] = vr0;
    *(uint4*)&Vs[(sr + 32) * LP + scol] = vr1;
    if (cI < qhi) {  // prefetch next chunk while computing this one
      const int kn = kc + 64;
      kr0 = *(const uint4*)(Kg + (size_t)(kn + sr) * HS + scol);
      kr1 = *(const uint4*)(Kg + (size_t)(kn + sr + 32) * HS + scol);
      vr0 = *(const uint4*)(Vg + (size_t)sr * SEQ + kn + scol);
      vr1 = *(const uint4*)(Vg + (size_t)(sr + 32) * SEQ + kn + scol);
    }
    __syncthreads();

    // K fragments (A-operand), shared across both tiles
    v8bf kf0[4], kf1[4];
#pragma unroll
    for (int ni = 0; ni < 4; ni++) {
      kf0[ni] = *(const v8bf*)&Ks[(ni * 16 + l15) * LP + quad * 8];
      kf1[ni] = *(const v8bf*)&Ks[(ni * 16 + l15) * LP + 32 + quad * 8];
    }

    const bool doLo = (cI <= qlo);

    // ---- hi tile: S^T = K Q^T, D[key=quad*4+r][qrow=l15] ----
    {
      v4f sc[4] = {};
#pragma unroll
      for (int ni = 0; ni < 4; ni++) {
        sc[ni] = MFMA16(kf0[ni], bq[1][0], sc[ni]);
        sc[ni] = MFMA16(kf1[ni], bq[1][1], sc[ni]);
      }
      if (cI == qhi) {
#pragma unroll
        for (int ni = 0; ni < 4; ni++) {
          const int key = kc + ni * 16 + quad * 4;
#pragma unroll
          for (int r = 0; r < 4; r++)
            if (key + r > qrow_hi) sc[ni][r] = -1e30f;
        }
      }
#pragma unroll
      for (int ni = 0; ni < 4; ni++) {
        const float p0 = exp2f(sc[ni][0]), p1 = exp2f(sc[ni][1]);
        const float p2 = exp2f(sc[ni][2]), p3 = exp2f(sc[ni][3]);
        uint2 pk;
        pk.x = __builtin_amdgcn_perm(__float_as_uint(p1), __float_as_uint(p0), 0x07060302u);
        pk.y = __builtin_amdgcn_perm(__float_as_uint(p3), __float_as_uint(p2), 0x07060302u);
        *(uint2*)&Ps_w[(16 + l15) * LP + ni * 16 + quad * 4] = pk;
      }
    }
    // ---- lo tile (wave-uniform skip once cI > qlo) ----
    if (doLo) {
      v4f sc[4] = {};
#pragma unroll
      for (int ni = 0; ni < 4; ni++) {
        sc[ni] = MFMA16(kf0[ni], bq[0][0], sc[ni]);
        sc[ni] = MFMA16(kf1[ni], bq[0][1], sc[ni]);
      }
      if (cI == qlo) {
#pragma unroll
        for (int ni = 0; ni < 4; ni++) {
          const int key = kc + ni * 16 + quad * 4;
#pragma unroll
          for (int r = 0; r < 4; r++)
            if (key + r > qrow_lo) sc[ni][r] = -1e30f;
        }
      }
#pragma unroll
      for (int ni = 0; ni < 4; ni++) {
        const float p0 = exp2f(sc[ni][0]), p1 = exp2f(sc[ni][1]);
        const float p2 = exp2f(sc[ni][2]), p3 = exp2f(sc[ni][3]);
        uint2 pk;
        pk.x = __builtin_amdgcn_perm(__float_as_uint(p1), __float_as_uint(p0), 0x07060302u);
        pk.y = __builtin_amdgcn_perm(__float_as_uint(p3), __float_as_uint(p2), 0x07060302u);
        *(uint2*)&Ps_w[l15 * LP + ni * 16 + quad * 4] = pk;
      }
    }

    // ---- O += P @ V, l += P @ 1; V fragments shared across tiles ----
#pragma unroll
    for (int ki = 0; ki < 2; ki++) {
      v8bf pahi = *(const v8bf*)&Ps_w[(16 + l15) * LP + ki * 32 + quad * 8];
      lacc[1] = MFMA16(pahi, ones, lacc[1]);
      v8bf palo;
      if (doLo) {
        palo = *(const v8bf*)&Ps_w[l15 * LP + ki * 32 + quad * 8];
        lacc[0] = MFMA16(palo, ones, lacc[0]);
      }
#pragma unroll
      for (int ni = 0; ni < 4; ni++) {
        v8bf vb = *(const v8bf*)&Vs[(ni * 16 + l15) * LP + ki * 32 + quad * 8];
        o[1][ni] = MFMA16(pahi, vb, o[1][ni]);
        if (doLo) o[0][ni] = MFMA16(palo, vb, o[0][ni]);
      }
    }
  }

  // epilogue: normalize and store both tiles (C-layout rows = quad*4+r)
#pragma unroll
  for (int tl = 0; tl < 2; tl++) {
    const int q0 = tl ? q0hi : q0lo;
    const int row_base = q0 + w * 16 + quad * 4;
    float invl[4];
#pragma unroll
    for (int r = 0; r < 4; r++) invl[r] = 1.0f / lacc[tl][r];
#pragma unroll
    for (int ni = 0; ni < 4; ni++)
#pragma unroll
      for (int r = 0; r < 4; r++) {
        const int tr = b_ * SEQ + row_base + r;
        ATTN[(size_t)tr * HDIM + h * HS + ni * 16 + l15] = f2bf(o[tl][ni][r] * invl[r]);
      }
  }
}

// ---------------- GEMM2: out(4096x1024) = ATTN @ WOT^T, fp32 out ----------------
// 128x64 tiles -> 512 blocks (2/CU) for latency hiding.
__global__ __launch_bounds__(256) void gemm_out_kernel(
    const unsigned short* __restrict__ Ab, const unsigned short* __restrict__ Wt,
    float* __restrict__ out) {
  __shared__ unsigned short As[128 * 32];
  __shared__ unsigned short Bs[64 * 32];
  const int m0 = blockIdx.x * 128;
  const int n0 = blockIdx.y * 64;
  const int t = threadIdx.x;
  const int lane = t & 63, w = t >> 6;
  const int wm = w * 32;
  const int quad = lane >> 4, l15 = lane & 15;

  v4f acc[2][4] = {};

  const int rowA = t >> 2;
  const int colA = (t & 3) * 8;
  const unsigned short* gA = Ab + (size_t)(m0 + rowA) * HDIM + colA;
  const unsigned short* gB = Wt + (size_t)(n0 + rowA) * HDIM + colA;
  unsigned short* lA = &As[t * 8];
  unsigned short* lB = &Bs[t * 8];   // only first 64 rows' worth used

  for (int k0 = 0; k0 < HDIM; k0 += 32) {
    __syncthreads();
    async16(gA + k0, lA);
    async16(gA + 64 * HDIM + k0, lA + 64 * 32);
    if (rowA < 64) async16(gB + k0, lB);
    __syncthreads();
    v8bf a[2], b[4];
#pragma unroll
    for (int i = 0; i < 2; i++)
      a[i] = *(const v8bf*)&As[(wm + i * 16 + l15) * 32 + quad * 8];
#pragma unroll
    for (int j = 0; j < 4; j++)
      b[j] = *(const v8bf*)&Bs[(j * 16 + l15) * 32 + quad * 8];
#pragma unroll
    for (int i = 0; i < 2; i++)
#pragma unroll
      for (int j = 0; j < 4; j++)
        acc[i][j] = MFMA16(a[i], b[j], acc[i][j]);
  }

#pragma unroll
  for (int i = 0; i < 2; i++) {
#pragma unroll
    for (int j = 0; j < 4; j++) {
#pragma unroll
      for (int r = 0; r < 4; r++) {
        const int tr = m0 + wm + i * 16 + quad * 4 + r;
        const int c = n0 + j * 16 + l15;
        out[(size_t)tr * HDIM + c] = acc[i][j][r];
      }
    }
  }
}

extern "C" void kernel_launch(void* const* d_in, const int* in_sizes, int n_in,
                              void* d_out, int out_size, void* d_ws, size_t ws_size,
                              hipStream_t stream) {
  (void)in_sizes; (void)n_in; (void)out_size; (void)ws_size;
  const float* x    = (const float*)d_in[0];
  const float* pos  = (const float*)d_in[1];
  const float* Wqkv = (const float*)d_in[2];
  const float* Wout = (const float*)d_in[3];
  float* out = (float*)d_out;

  char* ws = (char*)d_ws;
  unsigned short* XP   = (unsigned short*)(ws);
  unsigned short* X    = (unsigned short*)(ws + ((size_t)8  << 20));
  unsigned short* WQT  = (unsigned short*)(ws + ((size_t)16 << 20));
  unsigned short* WOT  = (unsigned short*)(ws + ((size_t)22 << 20));
  unsigned short* Qb   = (unsigned short*)(ws + ((size_t)24 << 20));
  unsigned short* Kb   = (unsigned short*)(ws + ((size_t)32 << 20));
  unsigned short* VTb  = (unsigned short*)(ws + ((size_t)40 << 20));
  unsigned short* ATTN = (unsigned short*)(ws + ((size_t)48 << 20));

  prep_all_kernel<<<8192, 256, 0, stream>>>(x, pos, Wqkv, Wout, X, XP, WQT, WOT);

  dim3 g1(TOKENS / 128, 3 * HDIM / 128);
  gemm_qkv_kernel<<<g1, 256, 0, stream>>>(XP, X, WQT, Qb, Kb, VTb);

  dim3 g2(2 * NHEADS, 16);
  attn_pair_kernel<<<g2, 256, 0, stream>>>(Qb, Kb, VTb, ATTN);

  dim3 g3(TOKENS / 128, HDIM / 64);
  gemm_out_kernel<<<g3, 256, 0, stream>>>(ATTN, WOT, out);
}